// Round 6
// baseline (250.229 us; speedup 1.0000x reference)
//
// PointNet++ FP: three_nn + three_interpolate + pointwise MLP(384->256->128)
// Round 6:
//  - three_nn: 512-thr blocks (8 wave-uniform chunks x 256 cand) -> 32
//    waves/CU; ping-pong s_load prefetch WITHOUT register copies (r5's
//    cur=buf copies cost ~4 v_mov/candidate -> 28 ops/cand issued vs 14).
//  - fused_mlp: 32-pt tiles (LDS 25KB -> 6 blocks/CU, grid 2048 = 8/CU for
//    cross-block phase overlap) keeping r5's coalesced wave-per-point gather;
//    launch_bounds(256,6); unroll-4 gather for load pipelining.
// MFMA 16x16x32 bf16 layouts (learn_hip m89/m120 verified):
//   A: [m=lane&15][k=(lane>>4)*8+j]   B: [k=(lane>>4)*8+j][n=lane&15]
//   D: [row=(lane>>4)*4+reg][col=lane&15]
#include <hip/hip_runtime.h>

typedef __bf16 bf16_t;
typedef bf16_t bf16x2_t __attribute__((ext_vector_type(2)));
typedef bf16_t bf16x4_t __attribute__((ext_vector_type(4)));
typedef bf16_t bf16x8_t __attribute__((ext_vector_type(8)));
typedef float floatx4_t __attribute__((ext_vector_type(4)));

constexpr int B_ = 8, N_ = 8192, M_ = 2048;
constexpr int C1 = 128, C2 = 256;
constexpr int K1 = 384, N1 = 256, N2 = 128;

// ws layout (bytes)
constexpr size_t WS_IDX   = 0;         // int   [8*8192*3]  = 786432 B
constexpr size_t WS_WGT   = 786432;    // float [8*8192*3]  = 786432 B
constexpr size_t WS_W1T   = 1572864;   // bf16  [256][384]  = 196608 B
constexpr size_t WS_W2T   = 1769472;   // bf16  [128][256]  =  65536 B
constexpr size_t WS_XYZ2P = 1835008;   // float4[8*2048]    = 262144 B
// total 2 MiB

// ---------------------------------------------------------------- prep ----
__global__ __launch_bounds__(256) void prep_kernel(
    const float* __restrict__ W1, const float* __restrict__ W2,
    const float* __restrict__ xyz2,
    bf16_t* __restrict__ W1T, bf16_t* __restrict__ W2T,
    float4* __restrict__ xyz2p) {
  int bid = blockIdx.x, tid = threadIdx.x;
  if (bid < 384) {                       // W1 [384][256] -> W1T [256][384]
    int t = bid * 256 + tid;             // 98304 elems
    int n = t / K1, k = t - n * K1;
    W1T[t] = (bf16_t)W1[k * N1 + n];
  } else if (bid < 512) {                // W2 [256][128] -> W2T [128][256]
    int t = (bid - 384) * 256 + tid;     // 32768 elems
    int n = t / N1, k = t - n * N1;
    W2T[t] = (bf16_t)W2[k * N2 + n];
  } else {                               // xyz2 -> float4{x,y,z,|q|^2}
    int t = (bid - 512) * 256 + tid;     // 16384 elems
    const float* p = xyz2 + (size_t)t * 3;
    float x = p[0], y = p[1], z = p[2];
    xyz2p[t] = make_float4(x, y, z, x * x + y * y + z * z);
  }
}

// ------------------------------------------------------------ three_nn ----
// Block = 512 threads (8 waves): 64 points x 8 wave-uniform chunks of 256
// candidates -> 4 blocks/CU = 32 waves/CU. Candidates via s_load_dwordx16
// groups, ping-pong prefetch with no register copies.
// d' = |q|^2 - 2*dot(p,q); true d2 = d' + |p|^2 (added before LDS merge).
// Branchless top-3 (values: min/med3; indices: cndmask on same compares);
// 4 independent chains for ILP, merged at end.
__global__ __launch_bounds__(512) void three_nn_kernel(
    const float* __restrict__ xyz1, const float4* __restrict__ xyz2p,
    int* __restrict__ idx_out, float* __restrict__ w_out) {
  __shared__ float sd[8][64][3];
  __shared__ int   si[8][64][3];

  int b = blockIdx.x >> 7;                   // 128 blocks per batch
  int n0 = (blockIdx.x & 127) << 6;          // 64 points per block
  int tid = threadIdx.x;
  int p = tid & 63;                          // point within tile
  // wave-uniform chunk id -> scalar (s_load) candidate path
  int c = __builtin_amdgcn_readfirstlane(tid >> 6);   // 0..7

  const float* p1 = xyz1 + ((size_t)b * N_ + n0 + p) * 3;
  float x = p1[0], y = p1[1], z = p1[2];
  float sq1 = x * x + y * y + z * z;
  float m2x = -2.0f * x, m2y = -2.0f * y, m2z = -2.0f * z;

  const float4* p2 = xyz2p + b * M_ + (c << 8);  // wave-uniform base, 256 cand
  int jbase = c << 8;

  float cd0[4], cd1[4], cd2[4];
  int   ci0[4], ci1[4], ci2[4];
#pragma unroll
  for (int t = 0; t < 4; ++t) {
    cd0[t] = 1e30f; cd1[t] = 1e30f; cd2[t] = 1e30f;
    ci0[t] = 0; ci1[t] = 0; ci2[t] = 0;
  }

  auto proc = [&](const float4& qv, int jj) {
    int tc = jj & 3;                         // chain id
    float d = fmaf(m2x, qv.x, fmaf(m2y, qv.y, fmaf(m2z, qv.z, qv.w)));
    bool l0 = d < cd0[tc], l1 = d < cd1[tc], l2 = d < cd2[tc];
    float n0v = fminf(cd0[tc], d);
    float n1v = __builtin_amdgcn_fmed3f(d, cd0[tc], cd1[tc]);
    float n2v = __builtin_amdgcn_fmed3f(d, cd1[tc], cd2[tc]);
    int t1 = l0 ? ci0[tc] : jj;              // carry into slot1
    int t2 = l1 ? ci1[tc] : jj;              // carry into slot2
    ci0[tc] = l0 ? jj : ci0[tc];
    ci1[tc] = l1 ? t1 : ci1[tc];
    ci2[tc] = l2 ? t2 : ci2[tc];
    cd0[tc] = n0v; cd1[tc] = n1v; cd2[tc] = n2v;
  };

  // ping-pong: bA holds group j, bB holds group j+8; no copies.
  float4 bA[8], bB[8];
#pragma unroll
  for (int t = 0; t < 8; ++t) bA[t] = p2[t];
  for (int j = 0; j < 256; j += 16) {
#pragma unroll
    for (int t = 0; t < 8; ++t) bB[t] = p2[j + 8 + t];   // j+15 <= 255 always
#pragma unroll
    for (int t = 0; t < 8; ++t) proc(bA[t], jbase + j + t);
    if (j + 16 < 256) {
#pragma unroll
      for (int t = 0; t < 8; ++t) bA[t] = p2[j + 16 + t];
    }
#pragma unroll
    for (int t = 0; t < 8; ++t) proc(bB[t], jbase + j + 8 + t);
  }

  // merge the 4 chains (once; branchy is fine here)
  float s0 = cd0[0], s1 = cd1[0], s2 = cd2[0];
  int i0 = ci0[0], i1 = ci1[0], i2 = ci2[0];
  auto ins = [&](float d, int j) {
    if (d < s2) {
      if (d < s1) {
        s2 = s1; i2 = i1;
        if (d < s0) { s1 = s0; i1 = i0; s0 = d; i0 = j; }
        else        { s1 = d;  i1 = j; }
      } else { s2 = d; i2 = j; }
    }
  };
#pragma unroll
  for (int t = 1; t < 4; ++t) {
    ins(cd0[t], ci0[t]); ins(cd1[t], ci1[t]); ins(cd2[t], ci2[t]);
  }

  // publish partials (true squared distances)
  sd[c][p][0] = s0 + sq1; si[c][p][0] = i0;
  sd[c][p][1] = s1 + sq1; si[c][p][1] = i1;
  sd[c][p][2] = s2 + sq1; si[c][p][2] = i2;
  __syncthreads();

  if (tid < 64) {
    float t0 = sd[0][tid][0], t1 = sd[0][tid][1], t2 = sd[0][tid][2];
    int   a0 = si[0][tid][0], a1 = si[0][tid][1], a2 = si[0][tid][2];
#pragma unroll
    for (int cc = 1; cc < 8; ++cc) {
#pragma unroll
      for (int k = 0; k < 3; ++k) {
        float d = sd[cc][tid][k];
        int   j = si[cc][tid][k];
        if (d < t2) {
          if (d < t1) {
            t2 = t1; a2 = a1;
            if (d < t0) { t1 = t0; a1 = a0; t0 = d; a0 = j; }
            else        { t1 = d;  a1 = j; }
          } else { t2 = d; a2 = j; }
        }
      }
    }
    float e0 = fmaxf(t0, 1e-10f), e1 = fmaxf(t1, 1e-10f), e2 = fmaxf(t2, 1e-10f);
    float r0 = 1.0f / e0, r1 = 1.0f / e1, r2 = 1.0f / e2;
    float rs = 1.0f / (r0 + r1 + r2);
    size_t base = ((size_t)b * N_ + n0 + tid) * 3;
    idx_out[base + 0] = a0; idx_out[base + 1] = a1; idx_out[base + 2] = a2;
    w_out[base + 0] = r0 * rs; w_out[base + 1] = r1 * rs; w_out[base + 2] = r2 * rs;
  }
}

// ------------------------------------------------------- fused interp+MLP --
// block = 256 threads (4 waves), 32 points/block, 2048 blocks (8/CU).
// Phase A: wave-per-point coalesced gather (lane l reads float4 at col 4l).
// Layer1: wave owns 64 cols, 2 row-tiles. Y1 overlays Xs. LDS 25088 B ->
// 6 blocks/CU resident; launch_bounds(256,6) caps VGPR accordingly.
__global__ __launch_bounds__(256, 6) void fused_mlp_kernel(
    const float* __restrict__ points1, const float* __restrict__ points2,
    const int* __restrict__ idx, const float* __restrict__ wgt,
    const bf16_t* __restrict__ W1T, const float* __restrict__ b1,
    const bf16_t* __restrict__ W2T, const float* __restrict__ b2,
    float* __restrict__ out) {
  __shared__ __align__(16) char smem[32 * 392 * 2];   // 25088 B
  bf16_t (*Xs)[392] = (bf16_t(*)[392])smem;           // phase 1: X[32][384]
  bf16_t (*Y1)[264] = (bf16_t(*)[264])smem;           // phase 2 (overlay)

  int bi = blockIdx.x;
  int b = bi >> 8;                 // 256 tiles per batch
  int base = (bi & 255) * 32;      // first point of tile
  int tid = threadIdx.x;
  int wave = __builtin_amdgcn_readfirstlane(tid >> 6);
  int lane = tid & 63;
  size_t bN = (size_t)b * N_ + base;

  // ---- Phase A: X[32][384] = [interp(256) | points1(128)], 8 pts/wave,
  // whole wave loads one point's rows contiguously (coalesced 1KB/instr).
#pragma unroll 4
  for (int i = 0; i < 8; ++i) {
    int p = wave * 8 + i;                        // uniform per iteration
    size_t pt = bN + p;
    size_t ib = pt * 3;
    int j0 = idx[ib], j1 = idx[ib + 1], j2 = idx[ib + 2];    // scalar loads
    float w0 = wgt[ib], w1 = wgt[ib + 1], w2 = wgt[ib + 2];
    const float* g0 = points2 + ((size_t)b * M_ + j0) * C2;
    const float* g1 = points2 + ((size_t)b * M_ + j1) * C2;
    const float* g2 = points2 + ((size_t)b * M_ + j2) * C2;
    int c4 = lane * 4;
    float4 a0 = *(const float4*)(g0 + c4);
    float4 a1 = *(const float4*)(g1 + c4);
    float4 a2 = *(const float4*)(g2 + c4);
    bf16x4_t v;
    v[0] = (bf16_t)(w0 * a0.x + w1 * a1.x + w2 * a2.x);
    v[1] = (bf16_t)(w0 * a0.y + w1 * a1.y + w2 * a2.y);
    v[2] = (bf16_t)(w0 * a0.z + w1 * a1.z + w2 * a2.z);
    v[3] = (bf16_t)(w0 * a0.w + w1 * a1.w + w2 * a2.w);
    *(bf16x4_t*)(&Xs[p][c4]) = v;
    const float* pp1 = points1 + pt * C1;
    float2 s = *(const float2*)(pp1 + lane * 2);
    bf16x2_t v2; v2[0] = (bf16_t)s.x; v2[1] = (bf16_t)s.y;
    *(bf16x2_t*)(&Xs[p][256 + lane * 2]) = v2;
  }
  __syncthreads();

  int q = lane >> 4, r = lane & 15;

  // ---- Layer 1: [32 x 384] x [384 x 256] -> Y1, wave owns 64 cols
  floatx4_t acc[2][4] = {};
  const bf16_t* wp0 = W1T + (size_t)(wave * 64 +  0 + r) * K1;
  const bf16_t* wp1 = W1T + (size_t)(wave * 64 + 16 + r) * K1;
  const bf16_t* wp2 = W1T + (size_t)(wave * 64 + 32 + r) * K1;
  const bf16_t* wp3 = W1T + (size_t)(wave * 64 + 48 + r) * K1;
  for (int kk = 0; kk < 12; ++kk) {
    int k0 = kk * 32 + q * 8;
    bf16x8_t a0 = *(const bf16x8_t*)(&Xs[ 0 + r][k0]);
    bf16x8_t a1 = *(const bf16x8_t*)(&Xs[16 + r][k0]);
    bf16x8_t bb0 = *(const bf16x8_t*)(wp0 + k0);
    bf16x8_t bb1 = *(const bf16x8_t*)(wp1 + k0);
    bf16x8_t bb2 = *(const bf16x8_t*)(wp2 + k0);
    bf16x8_t bb3 = *(const bf16x8_t*)(wp3 + k0);
    acc[0][0] = __builtin_amdgcn_mfma_f32_16x16x32_bf16(a0, bb0, acc[0][0], 0, 0, 0);
    acc[1][0] = __builtin_amdgcn_mfma_f32_16x16x32_bf16(a1, bb0, acc[1][0], 0, 0, 0);
    acc[0][1] = __builtin_amdgcn_mfma_f32_16x16x32_bf16(a0, bb1, acc[0][1], 0, 0, 0);
    acc[1][1] = __builtin_amdgcn_mfma_f32_16x16x32_bf16(a1, bb1, acc[1][1], 0, 0, 0);
    acc[0][2] = __builtin_amdgcn_mfma_f32_16x16x32_bf16(a0, bb2, acc[0][2], 0, 0, 0);
    acc[1][2] = __builtin_amdgcn_mfma_f32_16x16x32_bf16(a1, bb2, acc[1][2], 0, 0, 0);
    acc[0][3] = __builtin_amdgcn_mfma_f32_16x16x32_bf16(a0, bb3, acc[0][3], 0, 0, 0);
    acc[1][3] = __builtin_amdgcn_mfma_f32_16x16x32_bf16(a1, bb3, acc[1][3], 0, 0, 0);
  }
  __syncthreads();   // Xs dead only when ALL waves finished layer-1 reads

  // bias + relu -> Y1 (bf16, overlays Xs)
#pragma unroll
  for (int rt = 0; rt < 2; ++rt) {
#pragma unroll
    for (int ct = 0; ct < 4; ++ct) {
      int nn = wave * 64 + ct * 16 + r;
      float bias = b1[nn];
#pragma unroll
      for (int reg = 0; reg < 4; ++reg) {
        int m = rt * 16 + q * 4 + reg;
        Y1[m][nn] = (bf16_t)fmaxf(acc[rt][ct][reg] + bias, 0.0f);
      }
    }
  }
  __syncthreads();

  // ---- Layer 2: [32 x 256] x [256 x 128] -> out, wave owns 32 cols
  floatx4_t acc2[2][2] = {};
  const bf16_t* vp0 = W2T + (size_t)(wave * 32 +  0 + r) * N1;
  const bf16_t* vp1 = W2T + (size_t)(wave * 32 + 16 + r) * N1;
  for (int kk = 0; kk < 8; ++kk) {
    int k0 = kk * 32 + q * 8;
    bf16x8_t a0 = *(const bf16x8_t*)(&Y1[ 0 + r][k0]);
    bf16x8_t a1 = *(const bf16x8_t*)(&Y1[16 + r][k0]);
    bf16x8_t bb0 = *(const bf16x8_t*)(vp0 + k0);
    bf16x8_t bb1 = *(const bf16x8_t*)(vp1 + k0);
    acc2[0][0] = __builtin_amdgcn_mfma_f32_16x16x32_bf16(a0, bb0, acc2[0][0], 0, 0, 0);
    acc2[1][0] = __builtin_amdgcn_mfma_f32_16x16x32_bf16(a1, bb0, acc2[1][0], 0, 0, 0);
    acc2[0][1] = __builtin_amdgcn_mfma_f32_16x16x32_bf16(a0, bb1, acc2[0][1], 0, 0, 0);
    acc2[1][1] = __builtin_amdgcn_mfma_f32_16x16x32_bf16(a1, bb1, acc2[1][1], 0, 0, 0);
  }
#pragma unroll
  for (int rt = 0; rt < 2; ++rt) {
#pragma unroll
    for (int ct = 0; ct < 2; ++ct) {
      int cc = wave * 32 + ct * 16 + r;
      float bias = b2[cc];
#pragma unroll
      for (int reg = 0; reg < 4; ++reg) {
        int m = rt * 16 + q * 4 + reg;
        out[(bN + m) * N2 + cc] = fmaxf(acc2[rt][ct][reg] + bias, 0.0f);
      }
    }
  }
}

// ----------------------------------------------------------------- launch --
extern "C" void kernel_launch(void* const* d_in, const int* in_sizes, int n_in,
                              void* d_out, int out_size, void* d_ws, size_t ws_size,
                              hipStream_t stream) {
  (void)in_sizes; (void)n_in; (void)out_size; (void)ws_size;
  const float* xyz1    = (const float*)d_in[0];
  const float* xyz2    = (const float*)d_in[1];
  const float* points1 = (const float*)d_in[2];
  const float* points2 = (const float*)d_in[3];
  const float* W1      = (const float*)d_in[4];
  const float* b1      = (const float*)d_in[5];
  const float* W2      = (const float*)d_in[6];
  const float* b2      = (const float*)d_in[7];
  float* out = (float*)d_out;
  char* ws = (char*)d_ws;
  int*    idx   = (int*)(ws + WS_IDX);
  float*  wgt   = (float*)(ws + WS_WGT);
  bf16_t* W1T   = (bf16_t*)(ws + WS_W1T);
  bf16_t* W2T   = (bf16_t*)(ws + WS_W2T);
  float4* xyz2p = (float4*)(ws + WS_XYZ2P);

  prep_kernel<<<576, 256, 0, stream>>>(W1, W2, xyz2, W1T, W2T, xyz2p);
  three_nn_kernel<<<1024, 512, 0, stream>>>(xyz1, xyz2p, idx, wgt);
  fused_mlp_kernel<<<2048, 256, 0, stream>>>(points1, points2, idx, wgt,
                                             W1T, b1, W2T, b2, out);
}

// Round 7
// 240.140 us; speedup vs baseline: 1.0420x; 1.0420x over previous
//
// PointNet++ FP: three_nn + three_interpolate + pointwise MLP(384->256->128)
// Round 7: ONE change vs r5's fused: XCD-aware batch swizzle (batch=bi&7,
// tile=bi>>3) so each XCD's points2 gather working set is its own batch's
// 2MB slice (L2-resident) instead of all 16.8MB (thrash -> L3/HBM queueing).
// fused otherwise = r5 (64-pt tile, VGPR 68; r6's 32-pt + VGPR-40 regressed).
// three_nn = r6 (512-thr, 8 wave-uniform chunks, ping-pong s_load prefetch).
// MFMA 16x16x32 bf16 layouts (learn_hip m89/m120 verified):
//   A: [m=lane&15][k=(lane>>4)*8+j]   B: [k=(lane>>4)*8+j][n=lane&15]
//   D: [row=(lane>>4)*4+reg][col=lane&15]
#include <hip/hip_runtime.h>

typedef __bf16 bf16_t;
typedef bf16_t bf16x2_t __attribute__((ext_vector_type(2)));
typedef bf16_t bf16x4_t __attribute__((ext_vector_type(4)));
typedef bf16_t bf16x8_t __attribute__((ext_vector_type(8)));
typedef float floatx4_t __attribute__((ext_vector_type(4)));

constexpr int B_ = 8, N_ = 8192, M_ = 2048;
constexpr int C1 = 128, C2 = 256;
constexpr int K1 = 384, N1 = 256, N2 = 128;

// ws layout (bytes)
constexpr size_t WS_IDX   = 0;         // int   [8*8192*3]  = 786432 B
constexpr size_t WS_WGT   = 786432;    // float [8*8192*3]  = 786432 B
constexpr size_t WS_W1T   = 1572864;   // bf16  [256][384]  = 196608 B
constexpr size_t WS_W2T   = 1769472;   // bf16  [128][256]  =  65536 B
constexpr size_t WS_XYZ2P = 1835008;   // float4[8*2048]    = 262144 B
// total 2 MiB

// ---------------------------------------------------------------- prep ----
__global__ __launch_bounds__(256) void prep_kernel(
    const float* __restrict__ W1, const float* __restrict__ W2,
    const float* __restrict__ xyz2,
    bf16_t* __restrict__ W1T, bf16_t* __restrict__ W2T,
    float4* __restrict__ xyz2p) {
  int bid = blockIdx.x, tid = threadIdx.x;
  if (bid < 384) {                       // W1 [384][256] -> W1T [256][384]
    int t = bid * 256 + tid;             // 98304 elems
    int n = t / K1, k = t - n * K1;
    W1T[t] = (bf16_t)W1[k * N1 + n];
  } else if (bid < 512) {                // W2 [256][128] -> W2T [128][256]
    int t = (bid - 384) * 256 + tid;     // 32768 elems
    int n = t / N1, k = t - n * N1;
    W2T[t] = (bf16_t)W2[k * N2 + n];
  } else {                               // xyz2 -> float4{x,y,z,|q|^2}
    int t = (bid - 512) * 256 + tid;     // 16384 elems
    const float* p = xyz2 + (size_t)t * 3;
    float x = p[0], y = p[1], z = p[2];
    xyz2p[t] = make_float4(x, y, z, x * x + y * y + z * z);
  }
}

// ------------------------------------------------------------ three_nn ----
// Block = 512 threads (8 waves): 64 points x 8 wave-uniform chunks of 256
// candidates. Candidates via s_load groups, ping-pong prefetch, no copies.
// Branchless top-3 (values: min/med3; indices: cndmask); 4 chains, merged.
__global__ __launch_bounds__(512) void three_nn_kernel(
    const float* __restrict__ xyz1, const float4* __restrict__ xyz2p,
    int* __restrict__ idx_out, float* __restrict__ w_out) {
  __shared__ float sd[8][64][3];
  __shared__ int   si[8][64][3];

  int b = blockIdx.x >> 7;                   // 128 blocks per batch
  int n0 = (blockIdx.x & 127) << 6;          // 64 points per block
  int tid = threadIdx.x;
  int p = tid & 63;                          // point within tile
  int c = __builtin_amdgcn_readfirstlane(tid >> 6);   // 0..7

  const float* p1 = xyz1 + ((size_t)b * N_ + n0 + p) * 3;
  float x = p1[0], y = p1[1], z = p1[2];
  float sq1 = x * x + y * y + z * z;
  float m2x = -2.0f * x, m2y = -2.0f * y, m2z = -2.0f * z;

  const float4* p2 = xyz2p + b * M_ + (c << 8);  // wave-uniform base, 256 cand
  int jbase = c << 8;

  float cd0[4], cd1[4], cd2[4];
  int   ci0[4], ci1[4], ci2[4];
#pragma unroll
  for (int t = 0; t < 4; ++t) {
    cd0[t] = 1e30f; cd1[t] = 1e30f; cd2[t] = 1e30f;
    ci0[t] = 0; ci1[t] = 0; ci2[t] = 0;
  }

  auto proc = [&](const float4& qv, int jj) {
    int tc = jj & 3;                         // chain id
    float d = fmaf(m2x, qv.x, fmaf(m2y, qv.y, fmaf(m2z, qv.z, qv.w)));
    bool l0 = d < cd0[tc], l1 = d < cd1[tc], l2 = d < cd2[tc];
    float n0v = fminf(cd0[tc], d);
    float n1v = __builtin_amdgcn_fmed3f(d, cd0[tc], cd1[tc]);
    float n2v = __builtin_amdgcn_fmed3f(d, cd1[tc], cd2[tc]);
    int t1 = l0 ? ci0[tc] : jj;              // carry into slot1
    int t2 = l1 ? ci1[tc] : jj;              // carry into slot2
    ci0[tc] = l0 ? jj : ci0[tc];
    ci1[tc] = l1 ? t1 : ci1[tc];
    ci2[tc] = l2 ? t2 : ci2[tc];
    cd0[tc] = n0v; cd1[tc] = n1v; cd2[tc] = n2v;
  };

  // ping-pong: bA holds group j, bB holds group j+8; no copies.
  float4 bA[8], bB[8];
#pragma unroll
  for (int t = 0; t < 8; ++t) bA[t] = p2[t];
  for (int j = 0; j < 256; j += 16) {
#pragma unroll
    for (int t = 0; t < 8; ++t) bB[t] = p2[j + 8 + t];
#pragma unroll
    for (int t = 0; t < 8; ++t) proc(bA[t], jbase + j + t);
    if (j + 16 < 256) {
#pragma unroll
      for (int t = 0; t < 8; ++t) bA[t] = p2[j + 16 + t];
    }
#pragma unroll
    for (int t = 0; t < 8; ++t) proc(bB[t], jbase + j + 8 + t);
  }

  // merge the 4 chains
  float s0 = cd0[0], s1 = cd1[0], s2 = cd2[0];
  int i0 = ci0[0], i1 = ci1[0], i2 = ci2[0];
  auto ins = [&](float d, int j) {
    if (d < s2) {
      if (d < s1) {
        s2 = s1; i2 = i1;
        if (d < s0) { s1 = s0; i1 = i0; s0 = d; i0 = j; }
        else        { s1 = d;  i1 = j; }
      } else { s2 = d; i2 = j; }
    }
  };
#pragma unroll
  for (int t = 1; t < 4; ++t) {
    ins(cd0[t], ci0[t]); ins(cd1[t], ci1[t]); ins(cd2[t], ci2[t]);
  }

  sd[c][p][0] = s0 + sq1; si[c][p][0] = i0;
  sd[c][p][1] = s1 + sq1; si[c][p][1] = i1;
  sd[c][p][2] = s2 + sq1; si[c][p][2] = i2;
  __syncthreads();

  if (tid < 64) {
    float t0 = sd[0][tid][0], t1 = sd[0][tid][1], t2 = sd[0][tid][2];
    int   a0 = si[0][tid][0], a1 = si[0][tid][1], a2 = si[0][tid][2];
#pragma unroll
    for (int cc = 1; cc < 8; ++cc) {
#pragma unroll
      for (int k = 0; k < 3; ++k) {
        float d = sd[cc][tid][k];
        int   j = si[cc][tid][k];
        if (d < t2) {
          if (d < t1) {
            t2 = t1; a2 = a1;
            if (d < t0) { t1 = t0; a1 = a0; t0 = d; a0 = j; }
            else        { t1 = d;  a1 = j; }
          } else { t2 = d; a2 = j; }
        }
      }
    }
    float e0 = fmaxf(t0, 1e-10f), e1 = fmaxf(t1, 1e-10f), e2 = fmaxf(t2, 1e-10f);
    float r0 = 1.0f / e0, r1 = 1.0f / e1, r2 = 1.0f / e2;
    float rs = 1.0f / (r0 + r1 + r2);
    size_t base = ((size_t)b * N_ + n0 + tid) * 3;
    idx_out[base + 0] = a0; idx_out[base + 1] = a1; idx_out[base + 2] = a2;
    w_out[base + 0] = r0 * rs; w_out[base + 1] = r1 * rs; w_out[base + 2] = r2 * rs;
  }
}

// ------------------------------------------------------- fused interp+MLP --
// r5 structure: 256 threads (4 waves), 64 points/block, wave-per-point
// coalesced gather, Y1 overlays Xs. NEW: XCD batch swizzle — batch = bi & 7,
// tile = bi >> 3, so each XCD's gather hits only its batch's 2MB points2
// slice (L2-resident) instead of thrashing all 16.8MB across 8 XCDs.
__global__ __launch_bounds__(256, 3) void fused_mlp_kernel(
    const float* __restrict__ points1, const float* __restrict__ points2,
    const int* __restrict__ idx, const float* __restrict__ wgt,
    const bf16_t* __restrict__ W1T, const float* __restrict__ b1,
    const bf16_t* __restrict__ W2T, const float* __restrict__ b2,
    float* __restrict__ out) {
  __shared__ __align__(16) char smem[64 * 392 * 2];   // 50176 B
  bf16_t (*Xs)[392] = (bf16_t(*)[392])smem;           // phase 1: X[64][384]
  bf16_t (*Y1)[264] = (bf16_t(*)[264])smem;           // phase 2 (overlay)

  int bi = blockIdx.x;
  int b = bi & 7;                  // XCD-aware: batch -> XCD (round-robin)
  int base = (bi >> 3) * 64;       // tile within batch (0..127)
  int tid = threadIdx.x;
  int wave = __builtin_amdgcn_readfirstlane(tid >> 6);
  int lane = tid & 63;
  size_t bN = (size_t)b * N_ + base;

  // ---- Phase A: X[64][384] = [interp(256) | points1(128)], 16 pts/wave,
  // whole wave loads one point's rows contiguously (coalesced 1KB/instr).
#pragma unroll 2
  for (int i = 0; i < 16; ++i) {
    int p = wave * 16 + i;                       // uniform per iteration
    size_t pt = bN + p;
    size_t ib = pt * 3;
    int j0 = idx[ib], j1 = idx[ib + 1], j2 = idx[ib + 2];    // scalar loads
    float w0 = wgt[ib], w1 = wgt[ib + 1], w2 = wgt[ib + 2];
    const float* g0 = points2 + ((size_t)b * M_ + j0) * C2;
    const float* g1 = points2 + ((size_t)b * M_ + j1) * C2;
    const float* g2 = points2 + ((size_t)b * M_ + j2) * C2;
    int c4 = lane * 4;
    float4 a0 = *(const float4*)(g0 + c4);
    float4 a1 = *(const float4*)(g1 + c4);
    float4 a2 = *(const float4*)(g2 + c4);
    bf16x4_t v;
    v[0] = (bf16_t)(w0 * a0.x + w1 * a1.x + w2 * a2.x);
    v[1] = (bf16_t)(w0 * a0.y + w1 * a1.y + w2 * a2.y);
    v[2] = (bf16_t)(w0 * a0.z + w1 * a1.z + w2 * a2.z);
    v[3] = (bf16_t)(w0 * a0.w + w1 * a1.w + w2 * a2.w);
    *(bf16x4_t*)(&Xs[p][c4]) = v;
    const float* pp1 = points1 + pt * C1;
    float2 s = *(const float2*)(pp1 + lane * 2);
    bf16x2_t v2; v2[0] = (bf16_t)s.x; v2[1] = (bf16_t)s.y;
    *(bf16x2_t*)(&Xs[p][256 + lane * 2]) = v2;
  }
  __syncthreads();

  int q = lane >> 4, r = lane & 15;

  // ---- Layer 1: [64 x 384] x [384 x 256] -> Y1, wave owns 64 cols
  floatx4_t acc[4][4] = {};
  const bf16_t* wp0 = W1T + (size_t)(wave * 64 +  0 + r) * K1;
  const bf16_t* wp1 = W1T + (size_t)(wave * 64 + 16 + r) * K1;
  const bf16_t* wp2 = W1T + (size_t)(wave * 64 + 32 + r) * K1;
  const bf16_t* wp3 = W1T + (size_t)(wave * 64 + 48 + r) * K1;
  for (int kk = 0; kk < 12; ++kk) {
    int k0 = kk * 32 + q * 8;
    bf16x8_t a0 = *(const bf16x8_t*)(&Xs[ 0 + r][k0]);
    bf16x8_t a1 = *(const bf16x8_t*)(&Xs[16 + r][k0]);
    bf16x8_t a2 = *(const bf16x8_t*)(&Xs[32 + r][k0]);
    bf16x8_t a3 = *(const bf16x8_t*)(&Xs[48 + r][k0]);
    bf16x8_t bb0 = *(const bf16x8_t*)(wp0 + k0);
    bf16x8_t bb1 = *(const bf16x8_t*)(wp1 + k0);
    bf16x8_t bb2 = *(const bf16x8_t*)(wp2 + k0);
    bf16x8_t bb3 = *(const bf16x8_t*)(wp3 + k0);
    acc[0][0] = __builtin_amdgcn_mfma_f32_16x16x32_bf16(a0, bb0, acc[0][0], 0, 0, 0);
    acc[1][0] = __builtin_amdgcn_mfma_f32_16x16x32_bf16(a1, bb0, acc[1][0], 0, 0, 0);
    acc[2][0] = __builtin_amdgcn_mfma_f32_16x16x32_bf16(a2, bb0, acc[2][0], 0, 0, 0);
    acc[3][0] = __builtin_amdgcn_mfma_f32_16x16x32_bf16(a3, bb0, acc[3][0], 0, 0, 0);
    acc[0][1] = __builtin_amdgcn_mfma_f32_16x16x32_bf16(a0, bb1, acc[0][1], 0, 0, 0);
    acc[1][1] = __builtin_amdgcn_mfma_f32_16x16x32_bf16(a1, bb1, acc[1][1], 0, 0, 0);
    acc[2][1] = __builtin_amdgcn_mfma_f32_16x16x32_bf16(a2, bb1, acc[2][1], 0, 0, 0);
    acc[3][1] = __builtin_amdgcn_mfma_f32_16x16x32_bf16(a3, bb1, acc[3][1], 0, 0, 0);
    acc[0][2] = __builtin_amdgcn_mfma_f32_16x16x32_bf16(a0, bb2, acc[0][2], 0, 0, 0);
    acc[1][2] = __builtin_amdgcn_mfma_f32_16x16x32_bf16(a1, bb2, acc[1][2], 0, 0, 0);
    acc[2][2] = __builtin_amdgcn_mfma_f32_16x16x32_bf16(a2, bb2, acc[2][2], 0, 0, 0);
    acc[3][2] = __builtin_amdgcn_mfma_f32_16x16x32_bf16(a3, bb2, acc[3][2], 0, 0, 0);
    acc[0][3] = __builtin_amdgcn_mfma_f32_16x16x32_bf16(a0, bb3, acc[0][3], 0, 0, 0);
    acc[1][3] = __builtin_amdgcn_mfma_f32_16x16x32_bf16(a1, bb3, acc[1][3], 0, 0, 0);
    acc[2][3] = __builtin_amdgcn_mfma_f32_16x16x32_bf16(a2, bb3, acc[2][3], 0, 0, 0);
    acc[3][3] = __builtin_amdgcn_mfma_f32_16x16x32_bf16(a3, bb3, acc[3][3], 0, 0, 0);
  }
  __syncthreads();   // Xs dead only when ALL waves finished layer-1 reads

  // bias + relu -> Y1 (bf16, overlays Xs)
#pragma unroll
  for (int rt = 0; rt < 4; ++rt) {
#pragma unroll
    for (int ct = 0; ct < 4; ++ct) {
      int nn = wave * 64 + ct * 16 + r;
      float bias = b1[nn];
#pragma unroll
      for (int reg = 0; reg < 4; ++reg) {
        int m = rt * 16 + q * 4 + reg;
        Y1[m][nn] = (bf16_t)fmaxf(acc[rt][ct][reg] + bias, 0.0f);
      }
    }
  }
  __syncthreads();

  // ---- Layer 2: [64 x 256] x [256 x 128] -> out, wave owns 32 cols
  floatx4_t acc2[4][2] = {};
  const bf16_t* vp0 = W2T + (size_t)(wave * 32 +  0 + r) * N1;
  const bf16_t* vp1 = W2T + (size_t)(wave * 32 + 16 + r) * N1;
  for (int kk = 0; kk < 8; ++kk) {
    int k0 = kk * 32 + q * 8;
    bf16x8_t a0 = *(const bf16x8_t*)(&Y1[ 0 + r][k0]);
    bf16x8_t a1 = *(const bf16x8_t*)(&Y1[16 + r][k0]);
    bf16x8_t a2 = *(const bf16x8_t*)(&Y1[32 + r][k0]);
    bf16x8_t a3 = *(const bf16x8_t*)(&Y1[48 + r][k0]);
    bf16x8_t bb0 = *(const bf16x8_t*)(vp0 + k0);
    bf16x8_t bb1 = *(const bf16x8_t*)(vp1 + k0);
    acc2[0][0] = __builtin_amdgcn_mfma_f32_16x16x32_bf16(a0, bb0, acc2[0][0], 0, 0, 0);
    acc2[1][0] = __builtin_amdgcn_mfma_f32_16x16x32_bf16(a1, bb0, acc2[1][0], 0, 0, 0);
    acc2[2][0] = __builtin_amdgcn_mfma_f32_16x16x32_bf16(a2, bb0, acc2[2][0], 0, 0, 0);
    acc2[3][0] = __builtin_amdgcn_mfma_f32_16x16x32_bf16(a3, bb0, acc2[3][0], 0, 0, 0);
    acc2[0][1] = __builtin_amdgcn_mfma_f32_16x16x32_bf16(a0, bb1, acc2[0][1], 0, 0, 0);
    acc2[1][1] = __builtin_amdgcn_mfma_f32_16x16x32_bf16(a1, bb1, acc2[1][1], 0, 0, 0);
    acc2[2][1] = __builtin_amdgcn_mfma_f32_16x16x32_bf16(a2, bb1, acc2[2][1], 0, 0, 0);
    acc2[3][1] = __builtin_amdgcn_mfma_f32_16x16x32_bf16(a3, bb1, acc2[3][1], 0, 0, 0);
  }
#pragma unroll
  for (int rt = 0; rt < 4; ++rt) {
#pragma unroll
    for (int ct = 0; ct < 2; ++ct) {
      int cc = wave * 32 + ct * 16 + r;
      float bias = b2[cc];
#pragma unroll
      for (int reg = 0; reg < 4; ++reg) {
        int m = rt * 16 + q * 4 + reg;
        out[(bN + m) * N2 + cc] = fmaxf(acc2[rt][ct][reg] + bias, 0.0f);
      }
    }
  }
}

// ----------------------------------------------------------------- launch --
extern "C" void kernel_launch(void* const* d_in, const int* in_sizes, int n_in,
                              void* d_out, int out_size, void* d_ws, size_t ws_size,
                              hipStream_t stream) {
  (void)in_sizes; (void)n_in; (void)out_size; (void)ws_size;
  const float* xyz1    = (const float*)d_in[0];
  const float* xyz2    = (const float*)d_in[1];
  const float* points1 = (const float*)d_in[2];
  const float* points2 = (const float*)d_in[3];
  const float* W1      = (const float*)d_in[4];
  const float* b1      = (const float*)d_in[5];
  const float* W2      = (const float*)d_in[6];
  const float* b2      = (const float*)d_in[7];
  float* out = (float*)d_out;
  char* ws = (char*)d_ws;
  int*    idx   = (int*)(ws + WS_IDX);
  float*  wgt   = (float*)(ws + WS_WGT);
  bf16_t* W1T   = (bf16_t*)(ws + WS_W1T);
  bf16_t* W2T   = (bf16_t*)(ws + WS_W2T);
  float4* xyz2p = (float4*)(ws + WS_XYZ2P);

  prep_kernel<<<576, 256, 0, stream>>>(W1, W2, xyz2, W1T, W2T, xyz2p);
  three_nn_kernel<<<1024, 512, 0, stream>>>(xyz1, xyz2p, idx, wgt);
  fused_mlp_kernel<<<1024, 256, 0, stream>>>(points1, points2, idx, wgt,
                                             W1T, b1, W2T, b2, out);
}

// Round 8
// 228.331 us; speedup vs baseline: 1.0959x; 1.0517x over previous
//
// PointNet++ FP: three_nn + three_interpolate + pointwise MLP(384->256->128)
// Round 8: three_nn MERGED into the MLP kernel. Rationale (r7 counters):
// scan is pure VALU (81% busy, 0 mem), MLP is pure mem-latency (all pipes
// <10%). Serial kernels waste both; merged, co-resident blocks in different
// phases co-schedule VALU vs mem/MFMA (m114: overlap = max, not sum).
// idx/wgt stay in LDS (no HBM round-trip). XCD batch swizzle kept (b=bi&7).
// LDS: scan sd/si (6KB) overlaid by Xs[64][392] (50KB); iw/ww (1.5KB) kept
// live across phases. 51.7KB -> 3 blocks/CU.
// MFMA 16x16x32 bf16 layouts (learn_hip m89/m120 verified):
//   A: [m=lane&15][k=(lane>>4)*8+j]   B: [k=(lane>>4)*8+j][n=lane&15]
//   D: [row=(lane>>4)*4+reg][col=lane&15]
#include <hip/hip_runtime.h>

typedef __bf16 bf16_t;
typedef bf16_t bf16x2_t __attribute__((ext_vector_type(2)));
typedef bf16_t bf16x4_t __attribute__((ext_vector_type(4)));
typedef bf16_t bf16x8_t __attribute__((ext_vector_type(8)));
typedef float floatx4_t __attribute__((ext_vector_type(4)));

constexpr int B_ = 8, N_ = 8192, M_ = 2048;
constexpr int C1 = 128, C2 = 256;
constexpr int K1 = 384, N1 = 256, N2 = 128;

// ws layout (bytes)
constexpr size_t WS_W1T   = 0;         // bf16  [256][384]  = 196608 B
constexpr size_t WS_W2T   = 196608;    // bf16  [128][256]  =  65536 B
constexpr size_t WS_XYZ2P = 262144;    // float4[8*2048]    = 262144 B

// ---------------------------------------------------------------- prep ----
__global__ __launch_bounds__(256) void prep_kernel(
    const float* __restrict__ W1, const float* __restrict__ W2,
    const float* __restrict__ xyz2,
    bf16_t* __restrict__ W1T, bf16_t* __restrict__ W2T,
    float4* __restrict__ xyz2p) {
  int bid = blockIdx.x, tid = threadIdx.x;
  if (bid < 384) {                       // W1 [384][256] -> W1T [256][384]
    int t = bid * 256 + tid;             // 98304 elems
    int n = t / K1, k = t - n * K1;
    W1T[t] = (bf16_t)W1[k * N1 + n];
  } else if (bid < 512) {                // W2 [256][128] -> W2T [128][256]
    int t = (bid - 384) * 256 + tid;     // 32768 elems
    int n = t / N1, k = t - n * N1;
    W2T[t] = (bf16_t)W2[k * N2 + n];
  } else {                               // xyz2 -> float4{x,y,z,|q|^2}
    int t = (bid - 512) * 256 + tid;     // 16384 elems
    const float* p = xyz2 + (size_t)t * 3;
    float x = p[0], y = p[1], z = p[2];
    xyz2p[t] = make_float4(x, y, z, x * x + y * y + z * z);
  }
}

// ---------------------------------------------- fused nn+interp+MLP -------
// 1024 blocks x 256 threads; block owns 64 points of batch b = bi&7.
// Phase S: wave c scans candidate chunk c (512 cand) for all 64 points
//   (lane=point) — s_load ping-pong, branchless min/med3 top-3, 4 chains.
// Merge: wave0 folds 4 chunk-partials -> idx/wgt in LDS.
// Phase A: wave-per-point coalesced gather -> Xs bf16 (overlays scan LDS).
// Then MFMA layer1 -> relu -> Y1 (overlays Xs) -> MFMA layer2 -> out.
__global__ __launch_bounds__(256, 3) void fp_fused_kernel(
    const float* __restrict__ xyz1, const float4* __restrict__ xyz2p,
    const float* __restrict__ points1, const float* __restrict__ points2,
    const bf16_t* __restrict__ W1T, const float* __restrict__ b1,
    const bf16_t* __restrict__ W2T, const float* __restrict__ b2,
    float* __restrict__ out) {
  __shared__ __align__(16) char smem[64 * 392 * 2];   // 50176 B (Xs / sd,si)
  __shared__ int   iwI[64][3];                        // survives into gather
  __shared__ float iwW[64][3];
  bf16_t (*Xs)[392] = (bf16_t(*)[392])smem;           // gather/L1 phase
  bf16_t (*Y1)[264] = (bf16_t(*)[264])smem;           // L2 phase (overlay)
  float (*sd)[64][3] = (float(*)[64][3])smem;         // scan phase [4][64][3]
  int   (*si)[64][3] = (int(*)[64][3])(smem + 3072);  // scan phase [4][64][3]

  int bi = blockIdx.x;
  int b = bi & 7;                  // XCD-aware: batch -> XCD (round-robin)
  int base = (bi >> 3) * 64;       // tile within batch (0..127)
  int tid = threadIdx.x;
  int wave = __builtin_amdgcn_readfirstlane(tid >> 6);  // 0..3
  int lane = tid & 63;
  size_t bN = (size_t)b * N_ + base;

  // ================= Phase S: three_nn (wave=chunk of 512, lane=point) ====
  {
    const float* p1 = xyz1 + (bN + lane) * 3;
    float x = p1[0], y = p1[1], z = p1[2];
    float sq1 = x * x + y * y + z * z;
    float m2x = -2.0f * x, m2y = -2.0f * y, m2z = -2.0f * z;

    const float4* p2 = xyz2p + b * M_ + (wave << 9);  // wave-uniform base
    int jbase = wave << 9;

    float cd0[4], cd1[4], cd2[4];
    int   ci0[4], ci1[4], ci2[4];
#pragma unroll
    for (int t = 0; t < 4; ++t) {
      cd0[t] = 1e30f; cd1[t] = 1e30f; cd2[t] = 1e30f;
      ci0[t] = 0; ci1[t] = 0; ci2[t] = 0;
    }
    auto proc = [&](const float4& qv, int jj) {
      int tc = jj & 3;                         // chain id (const after unroll)
      float d = fmaf(m2x, qv.x, fmaf(m2y, qv.y, fmaf(m2z, qv.z, qv.w)));
      bool l0 = d < cd0[tc], l1 = d < cd1[tc], l2 = d < cd2[tc];
      float n0v = fminf(cd0[tc], d);
      float n1v = __builtin_amdgcn_fmed3f(d, cd0[tc], cd1[tc]);
      float n2v = __builtin_amdgcn_fmed3f(d, cd1[tc], cd2[tc]);
      int t1 = l0 ? ci0[tc] : jj;              // carry into slot1
      int t2 = l1 ? ci1[tc] : jj;              // carry into slot2
      ci0[tc] = l0 ? jj : ci0[tc];
      ci1[tc] = l1 ? t1 : ci1[tc];
      ci2[tc] = l2 ? t2 : ci2[tc];
      cd0[tc] = n0v; cd1[tc] = n1v; cd2[tc] = n2v;
    };

    float4 bA[8], bB[8];
#pragma unroll
    for (int t = 0; t < 8; ++t) bA[t] = p2[t];
    for (int j = 0; j < 512; j += 16) {
#pragma unroll
      for (int t = 0; t < 8; ++t) bB[t] = p2[j + 8 + t];
#pragma unroll
      for (int t = 0; t < 8; ++t) proc(bA[t], jbase + j + t);
      if (j + 16 < 512) {
#pragma unroll
        for (int t = 0; t < 8; ++t) bA[t] = p2[j + 16 + t];
      }
#pragma unroll
      for (int t = 0; t < 8; ++t) proc(bB[t], jbase + j + 8 + t);
    }

    // merge the 4 chains
    float s0 = cd0[0], s1 = cd1[0], s2 = cd2[0];
    int i0 = ci0[0], i1 = ci1[0], i2 = ci2[0];
    auto ins = [&](float d, int j) {
      if (d < s2) {
        if (d < s1) {
          s2 = s1; i2 = i1;
          if (d < s0) { s1 = s0; i1 = i0; s0 = d; i0 = j; }
          else        { s1 = d;  i1 = j; }
        } else { s2 = d; i2 = j; }
      }
    };
#pragma unroll
    for (int t = 1; t < 4; ++t) {
      ins(cd0[t], ci0[t]); ins(cd1[t], ci1[t]); ins(cd2[t], ci2[t]);
    }
    sd[wave][lane][0] = s0 + sq1; si[wave][lane][0] = i0;
    sd[wave][lane][1] = s1 + sq1; si[wave][lane][1] = i1;
    sd[wave][lane][2] = s2 + sq1; si[wave][lane][2] = i2;
  }
  __syncthreads();

  if (tid < 64) {                 // wave 0 folds 4 chunk-partials
    float t0 = sd[0][tid][0], t1 = sd[0][tid][1], t2 = sd[0][tid][2];
    int   a0 = si[0][tid][0], a1 = si[0][tid][1], a2 = si[0][tid][2];
#pragma unroll
    for (int cc = 1; cc < 4; ++cc) {
#pragma unroll
      for (int k = 0; k < 3; ++k) {
        float d = sd[cc][tid][k];
        int   j = si[cc][tid][k];
        if (d < t2) {
          if (d < t1) {
            t2 = t1; a2 = a1;
            if (d < t0) { t1 = t0; a1 = a0; t0 = d; a0 = j; }
            else        { t1 = d;  a1 = j; }
          } else { t2 = d; a2 = j; }
        }
      }
    }
    float e0 = fmaxf(t0, 1e-10f), e1 = fmaxf(t1, 1e-10f), e2 = fmaxf(t2, 1e-10f);
    float r0 = 1.0f / e0, r1 = 1.0f / e1, r2 = 1.0f / e2;
    float rs = 1.0f / (r0 + r1 + r2);
    iwI[tid][0] = a0; iwI[tid][1] = a1; iwI[tid][2] = a2;
    iwW[tid][0] = r0 * rs; iwW[tid][1] = r1 * rs; iwW[tid][2] = r2 * rs;
  }
  __syncthreads();

  // ================= Phase A: gather -> Xs[64][384] bf16 ==================
  // (Xs overlays sd/si — dead after merge barrier; iwI/iwW stay live.)
#pragma unroll 2
  for (int i = 0; i < 16; ++i) {
    int p = wave * 16 + i;                       // uniform per iteration
    int j0 = __builtin_amdgcn_readfirstlane(iwI[p][0]);
    int j1 = __builtin_amdgcn_readfirstlane(iwI[p][1]);
    int j2 = __builtin_amdgcn_readfirstlane(iwI[p][2]);
    float w0 = iwW[p][0], w1 = iwW[p][1], w2 = iwW[p][2];
    const float* g0 = points2 + ((size_t)b * M_ + j0) * C2;
    const float* g1 = points2 + ((size_t)b * M_ + j1) * C2;
    const float* g2 = points2 + ((size_t)b * M_ + j2) * C2;
    int c4 = lane * 4;
    float4 a0 = *(const float4*)(g0 + c4);
    float4 a1 = *(const float4*)(g1 + c4);
    float4 a2 = *(const float4*)(g2 + c4);
    bf16x4_t v;
    v[0] = (bf16_t)(w0 * a0.x + w1 * a1.x + w2 * a2.x);
    v[1] = (bf16_t)(w0 * a0.y + w1 * a1.y + w2 * a2.y);
    v[2] = (bf16_t)(w0 * a0.z + w1 * a1.z + w2 * a2.z);
    v[3] = (bf16_t)(w0 * a0.w + w1 * a1.w + w2 * a2.w);
    *(bf16x4_t*)(&Xs[p][c4]) = v;
    const float* pp1 = points1 + (bN + p) * C1;
    float2 s = *(const float2*)(pp1 + lane * 2);
    bf16x2_t v2; v2[0] = (bf16_t)s.x; v2[1] = (bf16_t)s.y;
    *(bf16x2_t*)(&Xs[p][256 + lane * 2]) = v2;
  }
  __syncthreads();

  int q = lane >> 4, r = lane & 15;

  // ---- Layer 1: [64 x 384] x [384 x 256] -> Y1, wave owns 64 cols
  floatx4_t acc[4][4] = {};
  const bf16_t* wp0 = W1T + (size_t)(wave * 64 +  0 + r) * K1;
  const bf16_t* wp1 = W1T + (size_t)(wave * 64 + 16 + r) * K1;
  const bf16_t* wp2 = W1T + (size_t)(wave * 64 + 32 + r) * K1;
  const bf16_t* wp3 = W1T + (size_t)(wave * 64 + 48 + r) * K1;
  for (int kk = 0; kk < 12; ++kk) {
    int k0 = kk * 32 + q * 8;
    bf16x8_t a0 = *(const bf16x8_t*)(&Xs[ 0 + r][k0]);
    bf16x8_t a1 = *(const bf16x8_t*)(&Xs[16 + r][k0]);
    bf16x8_t a2 = *(const bf16x8_t*)(&Xs[32 + r][k0]);
    bf16x8_t a3 = *(const bf16x8_t*)(&Xs[48 + r][k0]);
    bf16x8_t bb0 = *(const bf16x8_t*)(wp0 + k0);
    bf16x8_t bb1 = *(const bf16x8_t*)(wp1 + k0);
    bf16x8_t bb2 = *(const bf16x8_t*)(wp2 + k0);
    bf16x8_t bb3 = *(const bf16x8_t*)(wp3 + k0);
    acc[0][0] = __builtin_amdgcn_mfma_f32_16x16x32_bf16(a0, bb0, acc[0][0], 0, 0, 0);
    acc[1][0] = __builtin_amdgcn_mfma_f32_16x16x32_bf16(a1, bb0, acc[1][0], 0, 0, 0);
    acc[2][0] = __builtin_amdgcn_mfma_f32_16x16x32_bf16(a2, bb0, acc[2][0], 0, 0, 0);
    acc[3][0] = __builtin_amdgcn_mfma_f32_16x16x32_bf16(a3, bb0, acc[3][0], 0, 0, 0);
    acc[0][1] = __builtin_amdgcn_mfma_f32_16x16x32_bf16(a0, bb1, acc[0][1], 0, 0, 0);
    acc[1][1] = __builtin_amdgcn_mfma_f32_16x16x32_bf16(a1, bb1, acc[1][1], 0, 0, 0);
    acc[2][1] = __builtin_amdgcn_mfma_f32_16x16x32_bf16(a2, bb1, acc[2][1], 0, 0, 0);
    acc[3][1] = __builtin_amdgcn_mfma_f32_16x16x32_bf16(a3, bb1, acc[3][1], 0, 0, 0);
    acc[0][2] = __builtin_amdgcn_mfma_f32_16x16x32_bf16(a0, bb2, acc[0][2], 0, 0, 0);
    acc[1][2] = __builtin_amdgcn_mfma_f32_16x16x32_bf16(a1, bb2, acc[1][2], 0, 0, 0);
    acc[2][2] = __builtin_amdgcn_mfma_f32_16x16x32_bf16(a2, bb2, acc[2][2], 0, 0, 0);
    acc[3][2] = __builtin_amdgcn_mfma_f32_16x16x32_bf16(a3, bb2, acc[3][2], 0, 0, 0);
    acc[0][3] = __builtin_amdgcn_mfma_f32_16x16x32_bf16(a0, bb3, acc[0][3], 0, 0, 0);
    acc[1][3] = __builtin_amdgcn_mfma_f32_16x16x32_bf16(a1, bb3, acc[1][3], 0, 0, 0);
    acc[2][3] = __builtin_amdgcn_mfma_f32_16x16x32_bf16(a2, bb3, acc[2][3], 0, 0, 0);
    acc[3][3] = __builtin_amdgcn_mfma_f32_16x16x32_bf16(a3, bb3, acc[3][3], 0, 0, 0);
  }
  __syncthreads();   // Xs dead only when ALL waves finished layer-1 reads

  // bias + relu -> Y1 (bf16, overlays Xs)
#pragma unroll
  for (int rt = 0; rt < 4; ++rt) {
#pragma unroll
    for (int ct = 0; ct < 4; ++ct) {
      int nn = wave * 64 + ct * 16 + r;
      float bias = b1[nn];
#pragma unroll
      for (int reg = 0; reg < 4; ++reg) {
        int m = rt * 16 + q * 4 + reg;
        Y1[m][nn] = (bf16_t)fmaxf(acc[rt][ct][reg] + bias, 0.0f);
      }
    }
  }
  __syncthreads();

  // ---- Layer 2: [64 x 256] x [256 x 128] -> out, wave owns 32 cols
  floatx4_t acc2[4][2] = {};
  const bf16_t* vp0 = W2T + (size_t)(wave * 32 +  0 + r) * N1;
  const bf16_t* vp1 = W2T + (size_t)(wave * 32 + 16 + r) * N1;
  for (int kk = 0; kk < 8; ++kk) {
    int k0 = kk * 32 + q * 8;
    bf16x8_t a0 = *(const bf16x8_t*)(&Y1[ 0 + r][k0]);
    bf16x8_t a1 = *(const bf16x8_t*)(&Y1[16 + r][k0]);
    bf16x8_t a2 = *(const bf16x8_t*)(&Y1[32 + r][k0]);
    bf16x8_t a3 = *(const bf16x8_t*)(&Y1[48 + r][k0]);
    bf16x8_t bb0 = *(const bf16x8_t*)(vp0 + k0);
    bf16x8_t bb1 = *(const bf16x8_t*)(vp1 + k0);
    acc2[0][0] = __builtin_amdgcn_mfma_f32_16x16x32_bf16(a0, bb0, acc2[0][0], 0, 0, 0);
    acc2[1][0] = __builtin_amdgcn_mfma_f32_16x16x32_bf16(a1, bb0, acc2[1][0], 0, 0, 0);
    acc2[2][0] = __builtin_amdgcn_mfma_f32_16x16x32_bf16(a2, bb0, acc2[2][0], 0, 0, 0);
    acc2[3][0] = __builtin_amdgcn_mfma_f32_16x16x32_bf16(a3, bb0, acc2[3][0], 0, 0, 0);
    acc2[0][1] = __builtin_amdgcn_mfma_f32_16x16x32_bf16(a0, bb1, acc2[0][1], 0, 0, 0);
    acc2[1][1] = __builtin_amdgcn_mfma_f32_16x16x32_bf16(a1, bb1, acc2[1][1], 0, 0, 0);
    acc2[2][1] = __builtin_amdgcn_mfma_f32_16x16x32_bf16(a2, bb1, acc2[2][1], 0, 0, 0);
    acc2[3][1] = __builtin_amdgcn_mfma_f32_16x16x32_bf16(a3, bb1, acc2[3][1], 0, 0, 0);
  }
#pragma unroll
  for (int rt = 0; rt < 4; ++rt) {
#pragma unroll
    for (int ct = 0; ct < 2; ++ct) {
      int cc = wave * 32 + ct * 16 + r;
      float bias = b2[cc];
#pragma unroll
      for (int reg = 0; reg < 4; ++reg) {
        int m = rt * 16 + q * 4 + reg;
        out[(bN + m) * N2 + cc] = fmaxf(acc2[rt][ct][reg] + bias, 0.0f);
      }
    }
  }
}

// ----------------------------------------------------------------- launch --
extern "C" void kernel_launch(void* const* d_in, const int* in_sizes, int n_in,
                              void* d_out, int out_size, void* d_ws, size_t ws_size,
                              hipStream_t stream) {
  (void)in_sizes; (void)n_in; (void)out_size; (void)ws_size;
  const float* xyz1    = (const float*)d_in[0];
  const float* xyz2    = (const float*)d_in[1];
  const float* points1 = (const float*)d_in[2];
  const float* points2 = (const float*)d_in[3];
  const float* W1      = (const float*)d_in[4];
  const float* b1      = (const float*)d_in[5];
  const float* W2      = (const float*)d_in[6];
  const float* b2      = (const float*)d_in[7];
  float* out = (float*)d_out;
  char* ws = (char*)d_ws;
  bf16_t* W1T   = (bf16_t*)(ws + WS_W1T);
  bf16_t* W2T   = (bf16_t*)(ws + WS_W2T);
  float4* xyz2p = (float4*)(ws + WS_XYZ2P);

  prep_kernel<<<576, 256, 0, stream>>>(W1, W2, xyz2, W1T, W2T, xyz2p);
  fp_fused_kernel<<<1024, 256, 0, stream>>>(xyz1, xyz2p, points1, points2,
                                            W1T, b1, W2T, b2, out);
}